// Round 4
// baseline (268.894 us; speedup 1.0000x reference)
//
#include <hip/hip_runtime.h>
#include <hip/hip_bf16.h>
#include <math.h>

// Problem constants (from reference)
#define BATCH 4
#define N_ANCHORS 211200
#define CHANNELS 256
#define FM_H 200
#define FM_W 176
#define NKP 4096
#define PLANE (FM_H * FM_W)                   // 35200 floats

#define BOXES_ELEMS (BATCH * N_ANCHORS * 7)   // 5,913,600
#define BEV_ELEMS   (BATCH * CHANNELS * NKP)  // 4,194,304

// Native clang vector type: __builtin_nontemporal_store requires this
// (HIP's float4 class type is rejected).
typedef float floatx4 __attribute__((ext_vector_type(4)));

// Split-plane parameters for the gather kernel.
// half0: stages rows [0, 104), owns keypoints with y0 in [0, 102]  (y1 <= 103)
// half1: stages rows [103, 200), owns keypoints with y0 in [103, 200]
#define H_SPLIT   103
#define ROWS_H0   104                          // 104*176*4 = 73216 B
#define ROWS_H1   97                           // 97*176*4  = 68288 B
#define GATHER_LDS_BYTES (ROWS_H0 * FM_W * 4)  // 73216 B -> 2 blocks/CU

// ---------------------------------------------------------------------------
// Kernel 1: VoxelNet box decode, LDS-staged (~roofline at ~15 us).
// 1024 boxes per 256-thread block; dense float4 G->LDS, decode in LDS
// (stride-7 dwords, gcd(7,32)=1 -> conflict-free), dense float4 LDS->G.
// ---------------------------------------------------------------------------
#define DEC_BOXES 1024
#define DEC_FLOATS (DEC_BOXES * 7)   // 7168

__global__ __launch_bounds__(256) void decode_kernel(
    const float* __restrict__ deltas,
    const float* __restrict__ anchors,
    float* __restrict__ out_boxes)
{
    __shared__ float ldsD[DEC_FLOATS];
    __shared__ float ldsA[DEC_FLOATS];

    const int tid = threadIdx.x;
    const size_t base = (size_t)blockIdx.x * DEC_FLOATS;

    const floatx4* gd = (const floatx4*)(deltas  + base);
    const floatx4* ga = (const floatx4*)(anchors + base);
    floatx4* ldd4 = (floatx4*)ldsD;
    floatx4* lda4 = (floatx4*)ldsA;

#pragma unroll
    for (int it = 0; it < 7; ++it) {
        int idx = tid + it * 256;
        ldd4[idx] = gd[idx];
        lda4[idx] = ga[idx];
    }
    __syncthreads();

#pragma unroll
    for (int m = 0; m < 4; ++m) {
        int box = tid + m * 256;
        float* d = ldsD + box * 7;
        float* a = ldsA + box * 7;
        float aw = a[3], al = a[4], ah = a[5];
        float dn = sqrtf(aw * aw + al * al);
        float o0 = d[0] * dn + a[0];
        float o1 = d[1] * dn + a[1];
        float o2 = d[2] * ah + a[2];
        float o3 = expf(d[3]) * aw;
        float o4 = expf(d[4]) * al;
        float o5 = expf(d[5]) * ah;
        float o6 = d[6] + a[6];
        d[0] = o0; d[1] = o1; d[2] = o2; d[3] = o3;
        d[4] = o4; d[5] = o5; d[6] = o6;
    }
    __syncthreads();

    floatx4* go = (floatx4*)(out_boxes + base);
#pragma unroll
    for (int it = 0; it < 7; ++it) {
        int idx = tid + it * 256;
        __builtin_nontemporal_store(ldd4[idx], go + idx);
    }
}

// ---------------------------------------------------------------------------
// Kernel 2: BEV bilinear gather, SPLIT plane-in-LDS.
// Block = (bc, half). Each half stages ~70 KB of its plane (73.2 KB LDS ->
// 2 blocks/CU, 32 waves/CU: staging of one block overlaps compute/drain of
// its co-resident sibling — fixes the 1-block/CU serialization of R2).
// Both halves compute the full grid math for every k (cheap, VALUBusy ~11%)
// and store only the k's whose y0 falls in their row range; each k is
// written exactly once across the two halves.
// Grid math replicates the reference exactly, including the grid flip and
// zeros-padding masks.
// ---------------------------------------------------------------------------
__global__ __launch_bounds__(1024) void bev_gather_kernel(
    const float* __restrict__ fm,          // [B, C, H, W]
    const float* __restrict__ kp,          // [B, K, 3]
    float* __restrict__ out_bev)           // [B, C, K]
{
    extern __shared__ float tile[];        // up to ROWS_H0 * FM_W floats

    const int tid  = threadIdx.x;
    const int blk  = blockIdx.x;
    const int half = blk & 1;
    const int bc   = blk >> 1;             // b*CHANNELS + c
    const int b    = bc >> 8;              // CHANNELS == 256

    const int row_lo = half ? H_SPLIT : 0;
    const int rows   = half ? ROWS_H1 : ROWS_H0;

    // Phase 1: stage rows [row_lo, row_lo+rows) of plane bc into LDS.
    // FM_W = 176 -> 44 float4 per row; fully coalesced.
    const floatx4* gp = (const floatx4*)(fm + (size_t)bc * PLANE + row_lo * FM_W);
    floatx4* lp = (floatx4*)tile;
    const int n4 = rows * (FM_W / 4);
    for (int i = tid; i < n4; i += 1024) lp[i] = gp[i];
    __syncthreads();

    const float* kpb  = kp + (size_t)b * NKP * 3;
    float*       outp = out_bev + (size_t)bc * NKP;

#pragma unroll
    for (int m = 0; m < NKP / 1024; ++m) {
        int k = tid + m * 1024;
        float kx = kpb[k * 3 + 0];
        float ky = kpb[k * 3 + 1];

        // indices = (xy - pixel_offset) / (voxel_size * stride); voxel=0.05, stride=8
        float ix_idx = kx / 0.4f;
        float iy_idx = (ky + 40.0f) / 0.4f;
        ix_idx = fminf(fmaxf(ix_idx, 0.0f), (float)(FM_W - 1));
        iy_idx = fminf(fmaxf(iy_idx, 0.0f), (float)(FM_H - 1));
        float nx = 2.0f * (ix_idx / (float)(FM_W - 2)) - 1.0f;
        float ny = 2.0f * (iy_idx / (float)(FM_H - 2)) - 1.0f;
        // grid flip: width coord gets ny, height coord gets nx
        float ix = (ny + 1.0f) * 0.5f * (float)(FM_W - 1);
        float iy = (nx + 1.0f) * 0.5f * (float)(FM_H - 1);

        float x0f = floorf(ix);
        float y0f = floorf(iy);
        float wx = ix - x0f;
        float wy = iy - y0f;
        int x0 = (int)x0f, y0 = (int)y0f;   // y0 in [0, 200], x0 in [0, 175]
        int x1 = x0 + 1,   y1 = y0 + 1;

        bool mine = half ? (y0 >= H_SPLIT) : (y0 < H_SPLIT);

        float vx1 = (x1 <= FM_W - 1) ? 1.0f : 0.0f;     // x0 always valid
        float vy0 = (y0 <= FM_H - 1) ? 1.0f : 0.0f;     // y0 can be 200
        float vy1 = (y1 <= FM_H - 1) ? 1.0f : 0.0f;

        int xc1 = min(x1, FM_W - 1);
        int yc0 = min(y0, FM_H - 1) - row_lo;           // LDS row index
        int yc1 = min(y1, FM_H - 1) - row_lo;
        // Clamp LDS rows into the staged window (only matters for !mine lanes,
        // whose result is discarded; keeps the ds_read in-bounds).
        yc0 = min(max(yc0, 0), rows - 1);
        yc1 = min(max(yc1, 0), rows - 1);

        float v00 = tile[yc0 * FM_W + x0 ] * vy0;
        float v01 = tile[yc0 * FM_W + xc1] * (vx1 * vy0);
        float v10 = tile[yc1 * FM_W + x0 ] * vy1;
        float v11 = tile[yc1 * FM_W + xc1] * (vx1 * vy1);

        float r = v00 * (1.0f - wx) * (1.0f - wy)
                + v01 * wx * (1.0f - wy)
                + v10 * (1.0f - wx) * wy
                + v11 * wx * wy;

        if (mine) __builtin_nontemporal_store(r, outp + k);
    }
}

extern "C" void kernel_launch(void* const* d_in, const int* in_sizes, int n_in,
                              void* d_out, int out_size, void* d_ws, size_t ws_size,
                              hipStream_t stream)
{
    const float* deltas  = (const float*)d_in[0];
    const float* anchors = (const float*)d_in[1];
    const float* fm      = (const float*)d_in[2];
    const float* kp      = (const float*)d_in[3];

    float* out_boxes = (float*)d_out;
    float* out_bev   = (float*)d_out + BOXES_ELEMS;

    // Allow >64KB dynamic LDS (host-side, idempotent, graph-capture safe).
    static bool attr_set = false;
    if (!attr_set) {
        (void)hipFuncSetAttribute((const void*)bev_gather_kernel,
                                  hipFuncAttributeMaxDynamicSharedMemorySize,
                                  GATHER_LDS_BYTES);
        attr_set = true;
    }

    {
        int blocks = (BATCH * N_ANCHORS) / DEC_BOXES;   // 825 exactly
        decode_kernel<<<blocks, 256, 0, stream>>>(deltas, anchors, out_boxes);
    }
    {
        int blocks = BATCH * CHANNELS * 2;               // 2048 half-plane blocks
        bev_gather_kernel<<<blocks, 1024, GATHER_LDS_BYTES, stream>>>(fm, kp, out_bev);
    }
}